// Round 1
// baseline (1493.983 us; speedup 1.0000x reference)
//
#include <hip/hip_runtime.h>
#include <math.h>

// ---------------------------------------------------------------------------
// CapsNet forward on MI355X. All fp32 (threshold 4.4e-5 forbids bf16 inputs).
// conv2 (97.8 GFLOP) dominates: split-K implicit GEMM on the vector ALU.
// ---------------------------------------------------------------------------

#define C1_BYTES   104857600u   // 256*256*400*4
#define PART_ELEMS 2359296      // 256*256*36
#define Y2_BYTES   9437184u

// ============================ conv1: 9x9 s1 + ReLU ==========================
// grid 2048 = 256 b * 8 cgroups(32ch); block 320 = 20 oy * 16 ct (2 ch each)
__global__ __launch_bounds__(320) void conv1_k(
    const float* __restrict__ inp, const float* __restrict__ W1,
    const float* __restrict__ b1, float* __restrict__ out) {
  __shared__ __align__(16) float img[784];
  __shared__ float wl[81 * 34];          // [tap][32ch] pad->34
  const int blk = blockIdx.x;
  const int b = blk >> 3;
  const int cbase = (blk & 7) * 32;
  const int t = threadIdx.x;

  const float4* src = (const float4*)(inp + b * 784);
  for (int idx = t; idx < 196; idx += 320) ((float4*)img)[idx] = src[idx];
  for (int idx = t; idx < 2592; idx += 320) {
    int c = idx / 81, tap = idx - c * 81;
    wl[tap * 34 + c] = W1[(cbase + c) * 81 + tap];
  }
  __syncthreads();

  const int oy = t >> 4;                 // 0..19
  const int ct = t & 15;                 // 2 channels each
  const int c0 = cbase + ct * 2;
  const float bias0 = b1[c0], bias1 = b1[c0 + 1];
  float acc0[20], acc1[20];
#pragma unroll
  for (int ox = 0; ox < 20; ox++) { acc0[ox] = bias0; acc1[ox] = bias1; }

#pragma unroll 1
  for (int i = 0; i < 9; i++) {
    float wr0[9], wr1[9];
#pragma unroll
    for (int j = 0; j < 9; j++) {
      float2 wv = *(const float2*)&wl[(i * 9 + j) * 34 + ct * 2];
      wr0[j] = wv.x; wr1[j] = wv.y;
    }
    float xr[28];
    const float4* rp = (const float4*)&img[(oy + i) * 28];
#pragma unroll
    for (int k = 0; k < 7; k++) {
      float4 v = rp[k];
      xr[4 * k] = v.x; xr[4 * k + 1] = v.y; xr[4 * k + 2] = v.z; xr[4 * k + 3] = v.w;
    }
#pragma unroll
    for (int j = 0; j < 9; j++)
#pragma unroll
      for (int ox = 0; ox < 20; ox++) {
        acc0[ox] = fmaf(xr[ox + j], wr0[j], acc0[ox]);
        acc1[ox] = fmaf(xr[ox + j], wr1[j], acc1[ox]);
      }
  }
  float* o0 = out + (b * 256 + c0) * 400 + oy * 20;
#pragma unroll
  for (int k = 0; k < 5; k++)
    ((float4*)o0)[k] = make_float4(fmaxf(acc0[4*k],0.f), fmaxf(acc0[4*k+1],0.f),
                                   fmaxf(acc0[4*k+2],0.f), fmaxf(acc0[4*k+3],0.f));
  float* o1 = o0 + 400;
#pragma unroll
  for (int k = 0; k < 5; k++)
    ((float4*)o1)[k] = make_float4(fmaxf(acc1[4*k],0.f), fmaxf(acc1[4*k+1],0.f),
                                   fmaxf(acc1[4*k+2],0.f), fmaxf(acc1[4*k+3],0.f));
}

// =================== conv2: 9x9 s2 implicit GEMM, split-K ===================
// grid 1024 = 32 bgroup(8b) * 4 octile(64oc) * 8 ksplit(32ic); block 128
// thread = (bs 0..7, oct 0..15): 36 pos x 4 oc accumulators
__global__ __launch_bounds__(128, 2) void conv2_k(
    const float* __restrict__ x, const float* __restrict__ W2,
    float* __restrict__ part) {
  __shared__ __align__(16) float xs[8 * 404];   // 8 images, pad 400->404
  __shared__ __align__(16) float ws[81 * 68];   // [tap][64oc] pad->68
  const int blk = blockIdx.x;
  const int bg = blk & 31;
  const int octile = (blk >> 5) & 3;
  const int ks = blk >> 7;
  const int bbase = bg * 8, ocbase = octile * 64, icbase = ks * 32;
  const int t = threadIdx.x;
  const int bs = t & 7;
  const int oct = t >> 3;                // 0..15

  float acc[6][6][4];
#pragma unroll
  for (int a = 0; a < 6; a++)
#pragma unroll
    for (int o = 0; o < 6; o++)
#pragma unroll
      for (int c = 0; c < 4; c++) acc[a][o][c] = 0.f;

#pragma unroll 1
  for (int ici = 0; ici < 32; ici++) {
    const int ic = icbase + ici;
    __syncthreads();
    // stage x: 8 * 400 floats as float4
    for (int idx = t; idx < 800; idx += 128) {
      int bs2 = idx / 100, w4 = idx - bs2 * 100;
      float4 v = ((const float4*)(x + ((bbase + bs2) * 256 + ic) * 400))[w4];
      *(float4*)&xs[bs2 * 404 + w4 * 4] = v;
    }
    // stage W2 slice transposed -> [tap][oc]
    for (int idx = t; idx < 5184; idx += 128) {
      int oc = idx / 81, tap = idx - oc * 81;
      ws[tap * 68 + oc] = W2[(ocbase + oc) * 20736 + ic * 81 + tap];
    }
    __syncthreads();

    const float* xb = &xs[bs * 404];
#pragma unroll 1
    for (int i = 0; i < 9; i++) {
      float4 wr[9];
#pragma unroll
      for (int j = 0; j < 9; j++) wr[j] = *(const float4*)&ws[(i * 9 + j) * 68 + oct * 4];
#pragma unroll
      for (int oyu = 0; oyu < 6; oyu++) {
        float xr[20];
        const float4* rp = (const float4*)&xb[(2 * oyu + i) * 20];
#pragma unroll
        for (int k = 0; k < 5; k++) {
          float4 v = rp[k];
          xr[4 * k] = v.x; xr[4 * k + 1] = v.y; xr[4 * k + 2] = v.z; xr[4 * k + 3] = v.w;
        }
#pragma unroll
        for (int j = 0; j < 9; j++)
#pragma unroll
          for (int ox = 0; ox < 6; ox++) {
            float xv = xr[2 * ox + j];
            acc[oyu][ox][0] = fmaf(xv, wr[j].x, acc[oyu][ox][0]);
            acc[oyu][ox][1] = fmaf(xv, wr[j].y, acc[oyu][ox][1]);
            acc[oyu][ox][2] = fmaf(xv, wr[j].z, acc[oyu][ox][2]);
            acc[oyu][ox][3] = fmaf(xv, wr[j].w, acc[oyu][ox][3]);
          }
      }
    }
  }
  // epilogue: partial[ks][b][oc][pos]
  const int bI = bbase + bs;
#pragma unroll
  for (int c = 0; c < 4; c++) {
    const int oc = ocbase + oct * 4 + c;
    float* p = part + ks * PART_ELEMS + (bI * 256 + oc) * 36;
#pragma unroll
    for (int oyu = 0; oyu < 6; oyu++)
#pragma unroll
      for (int ox = 0; ox < 6; ox++) p[oyu * 6 + ox] = acc[oyu][ox][c];
  }
}

// ====================== reduce split-K partials + bias ======================
__global__ __launch_bounds__(256) void reduce_k(
    const float* __restrict__ part, const float* __restrict__ b2,
    float* __restrict__ y2) {
  const int i = blockIdx.x * 256 + threadIdx.x;  // < 2359296
  const int oc = (i / 36) & 255;
  float s = b2[oc];
#pragma unroll
  for (int ks = 0; ks < 8; ks++) s += part[ks * PART_ELEMS + i];
  y2[i] = s;
}

// ================= primary caps squash + predictions + routing ==============
// grid 8192 = g*256 + b; block 256
__global__ __launch_bounds__(256) void caps_k(
    const float* __restrict__ y2, const float* __restrict__ Wcaps,
    const float* __restrict__ b_route, float* __restrict__ vpart) {
  __shared__ float u[288];       // [36][8]
  __shared__ float usc[36];
  __shared__ float up[5760];     // [36][160]
  __shared__ float bl[360];      // [36][10]
  __shared__ float cl[360];
  __shared__ float sv[160];
  __shared__ float vv[160];
  __shared__ float scale[10];
  const int blk = blockIdx.x;
  const int g = blk >> 8, b = blk & 255;
  const int t = threadIdx.x;

  for (int idx = t; idx < 288; idx += 256) {
    int s = idx >> 3, d = idx & 7;
    u[idx] = y2[(b * 256 + g * 8 + d) * 36 + s];
  }
  for (int idx = t; idx < 360; idx += 256) bl[idx] = b_route[g * 360 + idx];
  __syncthreads();
  if (t < 36) {
    float l2 = 0.f;
#pragma unroll
    for (int d = 0; d < 8; d++) { float v = u[t * 8 + d]; l2 = fmaf(v, v, l2); }
    float l = sqrtf(l2);
    usc[t] = (l2 / (1.f + l2)) / (l + 1e-8f);
  }
  __syncthreads();
  for (int idx = t; idx < 288; idx += 256) u[idx] *= usc[idx >> 3];
  __syncthreads();
  // up[s][k] = sum_d u[s][d] * Wcaps[g][s][d][k]
  for (int idx = t; idx < 5760; idx += 256) {
    int s = idx / 160, k = idx - s * 160;
    const float* wp = Wcaps + (g * 36 + s) * 8 * 160 + k;
    float a = 0.f;
#pragma unroll
    for (int d = 0; d < 8; d++) a = fmaf(u[s * 8 + d], wp[d * 160], a);
    up[idx] = a;
  }
  __syncthreads();

  for (int r = 0; r < 3; r++) {
    if (t < 36) {
      float m = bl[t * 10];
#pragma unroll
      for (int oc = 1; oc < 10; oc++) m = fmaxf(m, bl[t * 10 + oc]);
      float e[10]; float sum = 0.f;
#pragma unroll
      for (int oc = 0; oc < 10; oc++) { e[oc] = expf(bl[t * 10 + oc] - m); sum += e[oc]; }
      float inv = 1.f / sum;
#pragma unroll
      for (int oc = 0; oc < 10; oc++) cl[t * 10 + oc] = e[oc] * inv;
    }
    __syncthreads();
    if (t < 160) {
      const int oc = t >> 4;
      float a = 0.f;
#pragma unroll 1
      for (int s = 0; s < 36; s++) a = fmaf(cl[s * 10 + oc], up[s * 160 + t], a);
      sv[t] = a;
    }
    __syncthreads();
    if (t < 10) {
      float l2 = 0.f;
#pragma unroll
      for (int od = 0; od < 16; od++) { float v = sv[t * 16 + od]; l2 = fmaf(v, v, l2); }
      scale[t] = (l2 / (1.f + l2)) / (sqrtf(l2) + 1e-8f);
    }
    __syncthreads();
    if (t < 160) vv[t] = sv[t] * scale[t >> 4];
    __syncthreads();
    if (r < 2) {
      for (int idx = t; idx < 360; idx += 256) {
        int s = idx / 10, oc = idx - s * 10;
        float a = 0.f;
#pragma unroll
        for (int od = 0; od < 16; od++)
          a = fmaf(up[s * 160 + oc * 16 + od], vv[oc * 16 + od], a);
        bl[idx] += a;
      }
      __syncthreads();
    }
  }
  if (t < 160) vpart[(b * 32 + g) * 160 + t] = vv[t];
}

// ================== final: sum over groups + probs ==========================
__global__ __launch_bounds__(192) void final_k(
    const float* __restrict__ vpart, float* __restrict__ out) {
  __shared__ float v[160];
  const int b = blockIdx.x, t = threadIdx.x;
  if (t < 160) {
    float a = 0.f;
#pragma unroll 1
    for (int g = 0; g < 32; g++) a += vpart[(b * 32 + g) * 160 + t];
    v[t] = a;
    out[b * 160 + t] = a;
  }
  __syncthreads();
  if (t < 10) {
    float l2 = 0.f;
#pragma unroll
    for (int od = 0; od < 16; od++) { float x = v[t * 16 + od]; l2 = fmaf(x, x, l2); }
    out[40960 + b * 10 + t] = sqrtf(l2);
  }
}

// ===========================================================================
extern "C" void kernel_launch(void* const* d_in, const int* in_sizes, int n_in,
                              void* d_out, int out_size, void* d_ws, size_t ws_size,
                              hipStream_t stream) {
  const float* inp     = (const float*)d_in[0];
  const float* W1      = (const float*)d_in[1];
  const float* b1      = (const float*)d_in[2];
  const float* W2      = (const float*)d_in[3];
  const float* b2      = (const float*)d_in[4];
  const float* Wcaps   = (const float*)d_in[5];
  const float* b_route = (const float*)d_in[6];
  float* out = (float*)d_out;
  char* ws = (char*)d_ws;

  float* conv1out = (float*)(ws);                    // 104.9 MB, dead after conv2
  float* part     = (float*)(ws + C1_BYTES);         // 75.5 MB
  float* y2       = (float*)(ws);                    // aliases dead conv1out
  float* vpart    = (float*)(ws + Y2_BYTES);         // aliases dead conv1out

  conv1_k <<<2048, 320, 0, stream>>>(inp, W1, b1, conv1out);
  conv2_k <<<1024, 128, 0, stream>>>(conv1out, W2, part);
  reduce_k<<<9216, 256, 0, stream>>>(part, b2, y2);
  caps_k  <<<8192, 256, 0, stream>>>(y2, Wcaps, b_route, vpart);
  final_k <<<256, 192, 0, stream>>>(vpart, out);
}

// Round 2
// 1378.403 us; speedup vs baseline: 1.0839x; 1.0839x over previous
//
#include <hip/hip_runtime.h>
#include <math.h>

// ---------------------------------------------------------------------------
// CapsNet forward on MI355X. All fp32 (threshold 4.4e-5 forbids bf16 inputs).
// conv2 (97.8 GFLOP) dominates: split-K implicit GEMM on the vector ALU.
// R2: conv2 re-tiled 72 acc/thread, 256-thr blocks, 3 blocks/CU (12 waves/CU),
//     grid 768 = exact residency round, conflict-free W2 staging (oc-major).
// ---------------------------------------------------------------------------

#define C1_BYTES   104857600u   // 256*256*400*4
#define PART_ELEMS 2359296      // 256*256*36
#define Y2_BYTES   9437184u
#define KSPLIT     6

// ============================ conv1: 9x9 s1 + ReLU ==========================
// grid 2048 = 256 b * 8 cgroups(32ch); block 320 = 20 oy * 16 ct (2 ch each)
__global__ __launch_bounds__(320) void conv1_k(
    const float* __restrict__ inp, const float* __restrict__ W1,
    const float* __restrict__ b1, float* __restrict__ out) {
  __shared__ __align__(16) float img[784];
  __shared__ float wl[81 * 34];          // [tap][32ch] pad->34
  const int blk = blockIdx.x;
  const int b = blk >> 3;
  const int cbase = (blk & 7) * 32;
  const int t = threadIdx.x;

  const float4* src = (const float4*)(inp + b * 784);
  for (int idx = t; idx < 196; idx += 320) ((float4*)img)[idx] = src[idx];
  for (int idx = t; idx < 2592; idx += 320) {
    int c = idx / 81, tap = idx - c * 81;
    wl[tap * 34 + c] = W1[(cbase + c) * 81 + tap];
  }
  __syncthreads();

  const int oy = t >> 4;                 // 0..19
  const int ct = t & 15;                 // 2 channels each
  const int c0 = cbase + ct * 2;
  const float bias0 = b1[c0], bias1 = b1[c0 + 1];
  float acc0[20], acc1[20];
#pragma unroll
  for (int ox = 0; ox < 20; ox++) { acc0[ox] = bias0; acc1[ox] = bias1; }

#pragma unroll 1
  for (int i = 0; i < 9; i++) {
    float wr0[9], wr1[9];
#pragma unroll
    for (int j = 0; j < 9; j++) {
      float2 wv = *(const float2*)&wl[(i * 9 + j) * 34 + ct * 2];
      wr0[j] = wv.x; wr1[j] = wv.y;
    }
    float xr[28];
    const float4* rp = (const float4*)&img[(oy + i) * 28];
#pragma unroll
    for (int k = 0; k < 7; k++) {
      float4 v = rp[k];
      xr[4 * k] = v.x; xr[4 * k + 1] = v.y; xr[4 * k + 2] = v.z; xr[4 * k + 3] = v.w;
    }
#pragma unroll
    for (int j = 0; j < 9; j++)
#pragma unroll
      for (int ox = 0; ox < 20; ox++) {
        acc0[ox] = fmaf(xr[ox + j], wr0[j], acc0[ox]);
        acc1[ox] = fmaf(xr[ox + j], wr1[j], acc1[ox]);
      }
  }
  float* o0 = out + (b * 256 + c0) * 400 + oy * 20;
#pragma unroll
  for (int k = 0; k < 5; k++)
    ((float4*)o0)[k] = make_float4(fmaxf(acc0[4*k],0.f), fmaxf(acc0[4*k+1],0.f),
                                   fmaxf(acc0[4*k+2],0.f), fmaxf(acc0[4*k+3],0.f));
  float* o1 = o0 + 400;
#pragma unroll
  for (int k = 0; k < 5; k++)
    ((float4*)o1)[k] = make_float4(fmaxf(acc1[4*k],0.f), fmaxf(acc1[4*k+1],0.f),
                                   fmaxf(acc1[4*k+2],0.f), fmaxf(acc1[4*k+3],0.f));
}

// =================== conv2: 9x9 s2 implicit GEMM, split-K ===================
// grid 768 = 32 bgroup(8b) * 4 octile(64oc) * 6 ksplit(43/42 ic); block 256
// thread = (bs 0..7, oct 0..15, oyh 0..1): 18 pos x 4 oc = 72 accumulators
// 3 blocks/CU (LDS 33.7KB, VGPR<=170) -> 12 waves/CU, grid = 1 exact round.
__global__ __launch_bounds__(256, 3) void conv2_k(
    const float* __restrict__ x, const float* __restrict__ W2,
    float* __restrict__ part) {
  __shared__ __align__(16) float xs[8 * 404];   // 8 images, pad 400->404
  __shared__ __align__(16) float ws[81 * 64];   // [tap][64oc] stride 64
  const int blk = blockIdx.x;
  const int bg = blk & 31;
  const int octile = (blk >> 5) & 3;
  const int ks = blk >> 7;                       // 0..5
  const int bbase = bg * 8, ocbase = octile * 64;
  const int icbase = (ks < 4) ? ks * 43 : 172 + (ks - 4) * 42;
  const int icn = (ks < 4) ? 43 : 42;
  const int t = threadIdx.x;
  const int bs = t & 7;
  const int oct = (t >> 3) & 15;
  const int oyh = t >> 7;                        // 0/1 -> rows 0-2 / 3-5
  const int yb2 = oyh * 6;                       // input-row offset (2*3*oyh)

  float acc[3][6][4];
#pragma unroll
  for (int a = 0; a < 3; a++)
#pragma unroll
    for (int o = 0; o < 6; o++)
#pragma unroll
      for (int c = 0; c < 4; c++) acc[a][o][c] = 0.f;

#pragma unroll 1
  for (int ici = 0; ici < icn; ici++) {
    const int ic = icbase + ici;
    __syncthreads();
    // stage x: 8 * 400 floats as float4 (coalesced, conflict-free)
    for (int idx = t; idx < 800; idx += 256) {
      int bs2 = idx / 100, w4 = idx - bs2 * 100;
      float4 v = ((const float4*)(x + ((bbase + bs2) * 256 + ic) * 400))[w4];
      *(float4*)&xs[bs2 * 404 + w4 * 4] = v;
    }
    // stage W2 slice oc-major: LDS writes lane-stride-1 (conflict-free);
    // global reads are per-lane contiguous streams within one oc (L2-backed)
    for (int idx = t; idx < 5184; idx += 256) {
      int tap = idx >> 6, oc = idx & 63;
      ws[tap * 64 + oc] = W2[(ocbase + oc) * 20736 + ic * 81 + tap];
    }
    __syncthreads();

    const float* xb = &xs[bs * 404 + yb2 * 20];
#pragma unroll 1
    for (int i = 0; i < 9; i++) {
      float4 wr[9];
#pragma unroll
      for (int j = 0; j < 9; j++) wr[j] = *(const float4*)&ws[(i * 9 + j) * 64 + oct * 4];
#pragma unroll
      for (int oyu = 0; oyu < 3; oyu++) {
        float xr[20];
        const float4* rp = (const float4*)&xb[(2 * oyu + i) * 20];
#pragma unroll
        for (int k = 0; k < 5; k++) {
          float4 v = rp[k];
          xr[4 * k] = v.x; xr[4 * k + 1] = v.y; xr[4 * k + 2] = v.z; xr[4 * k + 3] = v.w;
        }
#pragma unroll
        for (int j = 0; j < 9; j++)
#pragma unroll
          for (int ox = 0; ox < 6; ox++) {
            float xv = xr[2 * ox + j];
            acc[oyu][ox][0] = fmaf(xv, wr[j].x, acc[oyu][ox][0]);
            acc[oyu][ox][1] = fmaf(xv, wr[j].y, acc[oyu][ox][1]);
            acc[oyu][ox][2] = fmaf(xv, wr[j].z, acc[oyu][ox][2]);
            acc[oyu][ox][3] = fmaf(xv, wr[j].w, acc[oyu][ox][3]);
          }
      }
    }
  }
  // epilogue: partial[ks][b][oc][pos], thread owns pos [18*oyh, 18*oyh+18)
  const int bI = bbase + bs;
#pragma unroll
  for (int c = 0; c < 4; c++) {
    const int oc = ocbase + oct * 4 + c;
    float* p = part + ks * PART_ELEMS + (bI * 256 + oc) * 36 + oyh * 18;
#pragma unroll
    for (int oyu = 0; oyu < 3; oyu++)
#pragma unroll
      for (int ox2 = 0; ox2 < 3; ox2++)
        *(float2*)&p[oyu * 6 + ox2 * 2] =
            make_float2(acc[oyu][ox2 * 2][c], acc[oyu][ox2 * 2 + 1][c]);
  }
}

// ====================== reduce split-K partials + bias ======================
__global__ __launch_bounds__(256) void reduce_k(
    const float* __restrict__ part, const float* __restrict__ b2,
    float* __restrict__ y2) {
  const int i = blockIdx.x * 256 + threadIdx.x;  // < 2359296
  const int oc = (i / 36) & 255;
  float s = b2[oc];
#pragma unroll
  for (int ks = 0; ks < KSPLIT; ks++) s += part[ks * PART_ELEMS + i];
  y2[i] = s;
}

// ================= primary caps squash + predictions + routing ==============
// grid 8192 = g*256 + b; block 256
__global__ __launch_bounds__(256) void caps_k(
    const float* __restrict__ y2, const float* __restrict__ Wcaps,
    const float* __restrict__ b_route, float* __restrict__ vpart) {
  __shared__ float u[288];       // [36][8]
  __shared__ float usc[36];
  __shared__ float up[5760];     // [36][160]
  __shared__ float bl[360];      // [36][10]
  __shared__ float cl[360];
  __shared__ float sv[160];
  __shared__ float vv[160];
  __shared__ float scale[10];
  const int blk = blockIdx.x;
  const int g = blk >> 8, b = blk & 255;
  const int t = threadIdx.x;

  for (int idx = t; idx < 288; idx += 256) {
    int s = idx >> 3, d = idx & 7;
    u[idx] = y2[(b * 256 + g * 8 + d) * 36 + s];
  }
  for (int idx = t; idx < 360; idx += 256) bl[idx] = b_route[g * 360 + idx];
  __syncthreads();
  if (t < 36) {
    float l2 = 0.f;
#pragma unroll
    for (int d = 0; d < 8; d++) { float v = u[t * 8 + d]; l2 = fmaf(v, v, l2); }
    float l = sqrtf(l2);
    usc[t] = (l2 / (1.f + l2)) / (l + 1e-8f);
  }
  __syncthreads();
  for (int idx = t; idx < 288; idx += 256) u[idx] *= usc[idx >> 3];
  __syncthreads();
  // up[s][k] = sum_d u[s][d] * Wcaps[g][s][d][k]
  for (int idx = t; idx < 5760; idx += 256) {
    int s = idx / 160, k = idx - s * 160;
    const float* wp = Wcaps + (g * 36 + s) * 8 * 160 + k;
    float a = 0.f;
#pragma unroll
    for (int d = 0; d < 8; d++) a = fmaf(u[s * 8 + d], wp[d * 160], a);
    up[idx] = a;
  }
  __syncthreads();

  for (int r = 0; r < 3; r++) {
    if (t < 36) {
      float m = bl[t * 10];
#pragma unroll
      for (int oc = 1; oc < 10; oc++) m = fmaxf(m, bl[t * 10 + oc]);
      float e[10]; float sum = 0.f;
#pragma unroll
      for (int oc = 0; oc < 10; oc++) { e[oc] = expf(bl[t * 10 + oc] - m); sum += e[oc]; }
      float inv = 1.f / sum;
#pragma unroll
      for (int oc = 0; oc < 10; oc++) cl[t * 10 + oc] = e[oc] * inv;
    }
    __syncthreads();
    if (t < 160) {
      const int oc = t >> 4;
      float a = 0.f;
#pragma unroll 1
      for (int s = 0; s < 36; s++) a = fmaf(cl[s * 10 + oc], up[s * 160 + t], a);
      sv[t] = a;
    }
    __syncthreads();
    if (t < 10) {
      float l2 = 0.f;
#pragma unroll
      for (int od = 0; od < 16; od++) { float v = sv[t * 16 + od]; l2 = fmaf(v, v, l2); }
      scale[t] = (l2 / (1.f + l2)) / (sqrtf(l2) + 1e-8f);
    }
    __syncthreads();
    if (t < 160) vv[t] = sv[t] * scale[t >> 4];
    __syncthreads();
    if (r < 2) {
      for (int idx = t; idx < 360; idx += 256) {
        int s = idx / 10, oc = idx - s * 10;
        float a = 0.f;
#pragma unroll
        for (int od = 0; od < 16; od++)
          a = fmaf(up[s * 160 + oc * 16 + od], vv[oc * 16 + od], a);
        bl[idx] += a;
      }
      __syncthreads();
    }
  }
  if (t < 160) vpart[(b * 32 + g) * 160 + t] = vv[t];
}

// ================== final: sum over groups + probs ==========================
__global__ __launch_bounds__(192) void final_k(
    const float* __restrict__ vpart, float* __restrict__ out) {
  __shared__ float v[160];
  const int b = blockIdx.x, t = threadIdx.x;
  if (t < 160) {
    float a = 0.f;
#pragma unroll 1
    for (int g = 0; g < 32; g++) a += vpart[(b * 32 + g) * 160 + t];
    v[t] = a;
    out[b * 160 + t] = a;
  }
  __syncthreads();
  if (t < 10) {
    float l2 = 0.f;
#pragma unroll
    for (int od = 0; od < 16; od++) { float x = v[t * 16 + od]; l2 = fmaf(x, x, l2); }
    out[40960 + b * 10 + t] = sqrtf(l2);
  }
}

// ===========================================================================
extern "C" void kernel_launch(void* const* d_in, const int* in_sizes, int n_in,
                              void* d_out, int out_size, void* d_ws, size_t ws_size,
                              hipStream_t stream) {
  const float* inp     = (const float*)d_in[0];
  const float* W1      = (const float*)d_in[1];
  const float* b1      = (const float*)d_in[2];
  const float* W2      = (const float*)d_in[3];
  const float* b2      = (const float*)d_in[4];
  const float* Wcaps   = (const float*)d_in[5];
  const float* b_route = (const float*)d_in[6];
  float* out = (float*)d_out;
  char* ws = (char*)d_ws;

  float* conv1out = (float*)(ws);                    // 104.9 MB, dead after conv2
  float* part     = (float*)(ws + C1_BYTES);         // 56.6 MB (6 chunks)
  float* y2       = (float*)(ws);                    // aliases dead conv1out
  float* vpart    = (float*)(ws + Y2_BYTES);         // aliases dead conv1out

  conv1_k <<<2048, 320, 0, stream>>>(inp, W1, b1, conv1out);
  conv2_k <<<768, 256, 0, stream>>>(conv1out, W2, part);
  reduce_k<<<9216, 256, 0, stream>>>(part, b2, y2);
  caps_k  <<<8192, 256, 0, stream>>>(y2, Wcaps, b_route, vpart);
  final_k <<<256, 192, 0, stream>>>(vpart, out);
}